// Round 2
// baseline (1943.562 us; speedup 1.0000x reference)
//
#include <hip/hip_runtime.h>
#include <math.h>

#define N_UE 16384
#define N_AP 128
#define NE   2097152
#define EGRID 1024      // blocks for edge kernels; must equal NPART
#define NPART 1024
#define NSB   256       // sort blocks
#define EPSB  (NE / NSB)

// ---------------------------------------------------------------------------
// init: Qua1[u][d] = x_ue[u]*Wm1_ua[0][d] + bm1_ua[d];  Pau1[a][d] = bm1_au[d]
// ---------------------------------------------------------------------------
__global__ __launch_bounds__(256) void init_kernel(
    const float* __restrict__ x_ue, const float* __restrict__ Wm1_ua,
    const float* __restrict__ bm1_ua, const float* __restrict__ bm1_au,
    float* __restrict__ Qua, float* __restrict__ Pau)
{
    int i = blockIdx.x * 256 + threadIdx.x;   // grid covers N_UE*32 exactly
    int u = i >> 5, d = i & 31;
    (void)u;
    Qua[i] = fmaf(x_ue[i >> 5], Wm1_ua[d], bm1_ua[d]);
    if (i < N_AP * 32) Pau[i] = bm1_au[d];
}

// ---------------------------------------------------------------------------
// CSR build: histogram -> column scan -> prefix scan -> scatter
// ---------------------------------------------------------------------------
__global__ __launch_bounds__(256) void hist_kernel(
    const int* __restrict__ src, int* __restrict__ hist_part)
{
    __shared__ int h[N_UE];
    for (int i = threadIdx.x; i < N_UE; i += 256) h[i] = 0;
    __syncthreads();
    const int b = blockIdx.x, beg = b * EPSB;
    for (int e = beg + threadIdx.x; e < beg + EPSB; e += 256)
        atomicAdd(&h[src[e]], 1);
    __syncthreads();
    for (int i = threadIdx.x; i < N_UE; i += 256) hist_part[b * N_UE + i] = h[i];
}

__global__ __launch_bounds__(256) void colscan_kernel(
    const int* __restrict__ hist_part, int* __restrict__ base, int* __restrict__ cnt)
{
    const int u = blockIdx.x * 256 + threadIdx.x;   // grid = N_UE/256
    int run = 0;
    for (int b = 0; b < NSB; ++b) {
        int t = hist_part[b * N_UE + u];
        base[b * N_UE + u] = run;
        run += t;
    }
    cnt[u] = run;
}

__global__ __launch_bounds__(256) void scan_kernel(
    const int* __restrict__ cnt, int* __restrict__ offs)
{
    __shared__ int ps[256];
    __shared__ int ps2[257];
    const int t = threadIdx.x;
    const int b0 = t * (N_UE / 256);
    int s = 0;
    for (int i = 0; i < N_UE / 256; ++i) s += cnt[b0 + i];
    ps[t] = s;
    __syncthreads();
    if (t == 0) {
        int r = 0;
        for (int i = 0; i < 256; ++i) { ps2[i] = r; r += ps[i]; }
        ps2[256] = r;
    }
    __syncthreads();
    int r = ps2[t];
    for (int i = 0; i < N_UE / 256; ++i) { offs[b0 + i] = r; r += cnt[b0 + i]; }
    if (t == 255) offs[N_UE] = ps2[256];
}

__global__ __launch_bounds__(256) void scatter_kernel(
    const int* __restrict__ src, const int* __restrict__ dst,
    const float2* __restrict__ e0ua, const float2* __restrict__ e0au,
    const int* __restrict__ base, const int* __restrict__ offs,
    int* __restrict__ dst_s, float4* __restrict__ eAB, int* __restrict__ perm)
{
    __shared__ int cursor[N_UE];
    const int b = blockIdx.x;
    for (int i = threadIdx.x; i < N_UE; i += 256)
        cursor[i] = offs[i] + base[b * N_UE + i];
    __syncthreads();
    const int beg = b * EPSB;
    for (int e = beg + threadIdx.x; e < beg + EPSB; e += 256) {
        int s = src[e];
        int pos = atomicAdd(&cursor[s], 1);
        dst_s[pos] = dst[e];
        float2 a = e0ua[e], c = e0au[e];
        eAB[pos] = make_float4(a.x, a.y, c.x, c.y);
        perm[pos] = e;
    }
}

// ---------------------------------------------------------------------------
// Fused per-node edge kernel over CSR (sorted by src). One 32-lane group per
// UE node (grid-stride); lane = feature dim. No global atomics anywhere.
// EUPD: e' = relu(Rue[u] + Rap[dst] + e @ Ec)  (in-place in eAB, or -> out)
// MSG : m_ua -> LDS agg_ap (atomic LDS, flushed to partials)
//       m_au -> register accumulate -> agg_ue[u] (one coalesced 128B store)
// ---------------------------------------------------------------------------
template<bool EUPD, bool MSG, bool WRITEOUT>
__global__ __launch_bounds__(256) void seg_edge_kernel(
    const int* __restrict__ offs, const int* __restrict__ dst_s,
    float4* __restrict__ eAB, const int* __restrict__ perm,
    const float2* __restrict__ RueA, const float2* __restrict__ RueB,
    const float2* __restrict__ RapA, const float2* __restrict__ RapB,
    const float* __restrict__ EcA, const float* __restrict__ EcB,
    const float* __restrict__ Qua, const float* __restrict__ Pau,
    const float* __restrict__ cu, const float* __restrict__ cw,
    float* __restrict__ agg_ue, float* __restrict__ partial_ap,
    float2* __restrict__ out_eua, float2* __restrict__ out_eau)
{
    __shared__ float pau_s[N_AP * 32];
    __shared__ float aggap_s[N_AP * 32];
    __shared__ float2 rapA_s[N_AP], rapB_s[N_AP];

    const int tid = threadIdx.x, lane = tid & 31, g = tid >> 5;

    float u0 = 0.f, u1 = 0.f, w0 = 0.f, w1 = 0.f;
    if constexpr (MSG) {
        u0 = cu[lane]; u1 = cu[32 + lane];
        w0 = cw[lane]; w1 = cw[32 + lane];
        for (int i = tid; i < N_AP * 32; i += 256) { aggap_s[i] = 0.f; pau_s[i] = Pau[i]; }
    }
    float c00 = 0.f, c01 = 0.f, c10 = 0.f, c11 = 0.f;
    float d00 = 0.f, d01 = 0.f, d10 = 0.f, d11 = 0.f;
    if constexpr (EUPD) {
        c00 = EcA[0]; c01 = EcA[1]; c10 = EcA[2]; c11 = EcA[3];
        d00 = EcB[0]; d01 = EcB[1]; d10 = EcB[2]; d11 = EcB[3];
        if (tid < N_AP) { rapA_s[tid] = RapA[tid]; rapB_s[tid] = RapB[tid]; }
    }
    __syncthreads();

    const int group   = blockIdx.x * 8 + g;
    const int ngroups = gridDim.x * 8;

    for (int u = group; u < N_UE; u += ngroups) {
        const int e0 = offs[u], e1 = offs[u + 1];
        float2 rua = make_float2(0.f, 0.f), rub = make_float2(0.f, 0.f);
        if constexpr (EUPD) { rua = RueA[u]; rub = RueB[u]; }
        float q = 0.f;
        if constexpr (MSG) q = Qua[u * 32 + lane];
        float acc = 0.f;
        for (int e = e0; e < e1; ++e) {
            const int dte = dst_s[e];          // broadcast load
            float4 eab = eAB[e];               // broadcast 16B load
            float2 ea = make_float2(eab.x, eab.y);
            float2 eb = make_float2(eab.z, eab.w);
            if constexpr (EUPD) {
                float2 ra = rapA_s[dte], rb = rapB_s[dte];
                float n0 = fmaxf(rua.x + ra.x + ea.x * c00 + ea.y * c10, 0.f);
                float n1 = fmaxf(rua.y + ra.y + ea.x * c01 + ea.y * c11, 0.f);
                float m0 = fmaxf(rub.x + rb.x + eb.x * d00 + eb.y * d10, 0.f);
                float m1 = fmaxf(rub.y + rb.y + eb.x * d01 + eb.y * d11, 0.f);
                ea = make_float2(n0, n1);
                eb = make_float2(m0, m1);
                if constexpr (WRITEOUT) {
                    if (lane == 0) {
                        int p = perm[e];
                        out_eua[p] = ea;
                        out_eau[p] = eb;
                    }
                } else {
                    if (lane == 0) eAB[e] = make_float4(n0, n1, m0, m1);
                }
            }
            if constexpr (MSG) {
                float mua = fmaxf(fmaf(ea.x, u0, fmaf(ea.y, u1, q)), 0.f);
                atomicAdd(&aggap_s[dte * 32 + lane], mua);           // LDS, bank-clean
                float mau = fmaxf(fmaf(eb.x, w0, fmaf(eb.y, w1, pau_s[dte * 32 + lane])), 0.f);
                acc += mau;
            }
        }
        if constexpr (MSG) agg_ue[u * 32 + lane] = acc;
    }
    if constexpr (MSG) {
        __syncthreads();
        float* outp = partial_ap + (size_t)blockIdx.x * (N_AP * 32);
        for (int i = tid; i < N_AP * 32; i += 256) outp[i] = aggap_s[i];
    }
}

// ---------------------------------------------------------------------------
// UE node update + next-layer tables (+ power head for LAST)
// ---------------------------------------------------------------------------
template<bool FIRST, bool LAST>
__global__ __launch_bounds__(256) void node_ue_kernel(
    const float* __restrict__ x_prev, const float* __restrict__ agg_ue,
    const float* __restrict__ Wu, const float* __restrict__ bu,
    const float* __restrict__ Wm_next, const float* __restrict__ bm_next,
    const float* __restrict__ WeUa, const float* __restrict__ WeUb,
    const float* __restrict__ Wp1, const float* __restrict__ bp1,
    const float* __restrict__ Wp2, const float* __restrict__ bp2,
    float* __restrict__ x_new, float* __restrict__ Qua_next,
    float2* __restrict__ RueA, float2* __restrict__ RueB,
    float2* __restrict__ ue_out)
{
    constexpr int KIN = FIRST ? 33 : 64;
    __shared__ float Wu_s[64 * 32];
    __shared__ float Wm_s[32 * 32];
    __shared__ float WeA_s[64], WeB_s[64];
    __shared__ float bu_s[32], bm_s[32];
    __shared__ float Wp1_s[32 * 16], bp1_s[16], Wp2_s[16];

    const int tid = threadIdx.x;
    for (int i = tid; i < KIN * 32; i += 256) Wu_s[i] = Wu[i];
    if (tid < 32) bu_s[tid] = bu[tid];
    if (!LAST) {
        for (int i = tid; i < 1024; i += 256) Wm_s[i] = Wm_next[i];
        if (tid < 32) bm_s[tid] = bm_next[tid];
    }
    if (tid < 64) { WeA_s[tid] = WeUa[tid]; WeB_s[tid] = WeUb[tid]; }
    if (LAST) {
        for (int i = tid; i < 512; i += 256) Wp1_s[i] = Wp1[i];
        if (tid < 16) { bp1_s[tid] = bp1[tid]; Wp2_s[tid] = Wp2[tid]; }
    }
    __syncthreads();

    const int u = blockIdx.x * 256 + tid;
    float in[KIN];
    if (FIRST) {
        in[0] = x_prev[u];
        #pragma unroll
        for (int k = 0; k < 32; ++k) in[1 + k] = agg_ue[u * 32 + k];
    } else {
        #pragma unroll
        for (int k = 0; k < 32; ++k) in[k] = x_prev[u * 32 + k];
        #pragma unroll
        for (int k = 0; k < 32; ++k) in[32 + k] = agg_ue[u * 32 + k];
    }
    float out[32];
    #pragma unroll
    for (int d = 0; d < 32; ++d) {
        float acc = bu_s[d];
        #pragma unroll
        for (int k = 0; k < KIN; ++k) acc = fmaf(in[k], Wu_s[k * 32 + d], acc);
        out[d] = fmaxf(acc, 0.f);
    }
    #pragma unroll
    for (int d = 0; d < 32; ++d) x_new[u * 32 + d] = out[d];
    if (!LAST) {
        #pragma unroll
        for (int d = 0; d < 32; ++d) {
            float acc = bm_s[d];
            #pragma unroll
            for (int k = 0; k < 32; ++k) acc = fmaf(out[k], Wm_s[k * 32 + d], acc);
            Qua_next[u * 32 + d] = acc;
        }
    }
    float r0 = 0.f, r1 = 0.f, s0 = 0.f, s1 = 0.f;
    #pragma unroll
    for (int k = 0; k < 32; ++k) {
        r0 = fmaf(out[k], WeA_s[k * 2],     r0);
        r1 = fmaf(out[k], WeA_s[k * 2 + 1], r1);
        s0 = fmaf(out[k], WeB_s[k * 2],     s0);
        s1 = fmaf(out[k], WeB_s[k * 2 + 1], s1);
    }
    RueA[u] = make_float2(r0, r1);
    RueB[u] = make_float2(s0, s1);
    if (LAST) {
        float z = bp2[0];
        #pragma unroll
        for (int j = 0; j < 16; ++j) {
            float h = bp1_s[j];
            #pragma unroll
            for (int k = 0; k < 32; ++k) h = fmaf(out[k], Wp1_s[k * 16 + j], h);
            z = fmaf(fmaxf(h, 0.f), Wp2_s[j], z);
        }
        float pw = 1.f / (1.f + expf(-z));
        ue_out[u] = make_float2(out[0], pw);
    }
}

// ---------------------------------------------------------------------------
// AP: reduce partials -> agg_ap, node update, next-layer tables
// ---------------------------------------------------------------------------
template<bool FIRST, bool LAST>
__global__ __launch_bounds__(256) void node_ap_kernel(
    const float* __restrict__ partial,
    const float* __restrict__ x_prev,
    const float* __restrict__ Wu, const float* __restrict__ bu,
    const float* __restrict__ Wm_next, const float* __restrict__ bm_next,
    const float* __restrict__ WeA, const float* __restrict__ beA,
    const float* __restrict__ WeB, const float* __restrict__ beB,
    float* __restrict__ x_new, float* __restrict__ Pau_next,
    float2* __restrict__ RapA, float2* __restrict__ RapB)
{
    __shared__ float red[256];
    __shared__ float agg_s[32];
    __shared__ float xnew_s[32];
    const int a = blockIdx.x, tid = threadIdx.x;
    const int d = tid & 31, p0 = tid >> 5;
    float acc = 0.f;
    for (int p = p0; p < NPART; p += 8)
        acc += partial[(size_t)p * (N_AP * 32) + a * 32 + d];
    red[tid] = acc;
    __syncthreads();
    if (tid < 32) {
        float s = 0.f;
        #pragma unroll
        for (int i = 0; i < 8; ++i) s += red[i * 32 + tid];
        agg_s[tid] = s;
    }
    __syncthreads();
    if (tid < 32) {
        float acc2 = bu[d];
        if (FIRST) {
            #pragma unroll
            for (int k = 0; k < 32; ++k) acc2 = fmaf(agg_s[k], Wu[k * 32 + d], acc2);
        } else {
            #pragma unroll
            for (int k = 0; k < 32; ++k) acc2 = fmaf(x_prev[a * 32 + k], Wu[k * 32 + d], acc2);
            #pragma unroll
            for (int k = 0; k < 32; ++k) acc2 = fmaf(agg_s[k], Wu[(32 + k) * 32 + d], acc2);
        }
        float xn = fmaxf(acc2, 0.f);
        xnew_s[d] = xn;
        x_new[a * 32 + d] = xn;
    }
    __syncthreads();
    if (!LAST) {
        if (tid < 32) {
            float acc3 = bm_next[d];
            #pragma unroll
            for (int k = 0; k < 32; ++k) acc3 = fmaf(xnew_s[k], Wm_next[k * 32 + d], acc3);
            Pau_next[a * 32 + d] = acc3;
        }
    }
    if (tid == 0) {
        float q0 = beA[0], q1 = beA[1], t0 = beB[0], t1 = beB[1];
        #pragma unroll
        for (int k = 0; k < 32; ++k) {
            q0 = fmaf(xnew_s[k], WeA[k * 2],     q0);
            q1 = fmaf(xnew_s[k], WeA[k * 2 + 1], q1);
            t0 = fmaf(xnew_s[k], WeB[k * 2],     t0);
            t1 = fmaf(xnew_s[k], WeB[k * 2 + 1], t1);
        }
        RapA[a] = make_float2(q0, q1);
        RapB[a] = make_float2(t0, t1);
    }
}

// ---------------------------------------------------------------------------
extern "C" void kernel_launch(void* const* d_in, const int* in_sizes, int n_in,
                              void* d_out_v, int out_size, void* d_ws, size_t ws_size,
                              hipStream_t stream)
{
    const float*  x_ue   = (const float*)d_in[0];
    const float2* e0ua   = (const float2*)d_in[1];
    const float2* e0au   = (const float2*)d_in[2];
    const int*    src    = (const int*)d_in[3];
    const int*    dst    = (const int*)d_in[4];
    const float* Wm1_ua = (const float*)d_in[5];
    const float* bm1_ua = (const float*)d_in[6];
    const float* Wm1_au = (const float*)d_in[7];
    const float* bm1_au = (const float*)d_in[8];
    const float* Wu1_ap = (const float*)d_in[9];
    const float* bu1_ap = (const float*)d_in[10];
    const float* Wu1_ue = (const float*)d_in[11];
    const float* bu1_ue = (const float*)d_in[12];
    const float* We1_ua = (const float*)d_in[13];
    const float* be1_ua = (const float*)d_in[14];
    const float* We1_au = (const float*)d_in[15];
    const float* be1_au = (const float*)d_in[16];
    const float* Wm_ua  = (const float*)d_in[17];
    const float* bm_ua  = (const float*)d_in[18];
    const float* Wm_au  = (const float*)d_in[19];
    const float* bm_au  = (const float*)d_in[20];
    const float* Wu_ap  = (const float*)d_in[21];
    const float* bu_ap  = (const float*)d_in[22];
    const float* Wu_ue  = (const float*)d_in[23];
    const float* bu_ue  = (const float*)d_in[24];
    const float* We_ua  = (const float*)d_in[25];
    const float* be_ua  = (const float*)d_in[26];
    const float* We_au  = (const float*)d_in[27];
    const float* be_au  = (const float*)d_in[28];
    const float* Wp1    = (const float*)d_in[29];
    const float* bp1    = (const float*)d_in[30];
    const float* Wp2    = (const float*)d_in[31];
    const float* bp2    = (const float*)d_in[32];

    float*  outp    = (float*)d_out_v;
    float2* out_ue  = (float2*)outp;                              // [16384][2]
    float*  out_ap  = outp + N_UE * 2;                            // [128][32]
    float2* out_eua = (float2*)(outp + N_UE * 2 + N_AP * 32);     // [E][2]
    float2* out_eau = (float2*)(outp + N_UE * 2 + N_AP * 32 + (size_t)NE * 2);

    float* ws = (float*)d_ws;
    float* x_ueA  = ws;          ws += N_UE * 32;
    float* x_ueB  = ws;          ws += N_UE * 32;
    float* x_apA  = ws;          ws += N_AP * 32;
    float* x_apB  = ws;          ws += N_AP * 32;
    float* agg_ue = ws;          ws += N_UE * 32;
    float* Qua    = ws;          ws += N_UE * 32;
    float* Pau    = ws;          ws += N_AP * 32;
    float2* RueA  = (float2*)ws; ws += N_UE * 2;
    float2* RueB  = (float2*)ws; ws += N_UE * 2;
    float2* RapA  = (float2*)ws; ws += N_AP * 2;
    float2* RapB  = (float2*)ws; ws += N_AP * 2;
    float* partial = ws;         ws += (size_t)NPART * N_AP * 32; // 16 MB
    int* base_mat  = (int*)partial;                               // alias: NSB*N_UE ints = 16 MB
    int* dst_s = (int*)ws;       ws += NE;
    int* perm  = (int*)ws;       ws += NE;
    int* cnt   = (int*)ws;       ws += N_UE;
    int* offs  = (int*)ws;       ws += N_UE + 1;
    float4* eAB = (float4*)ws;   ws += (size_t)NE * 4;            // 32 MB
    int* hist_part = (int*)eAB;                                   // alias: 16 MB, consumed before eAB written

    dim3 blk(256);

    // ---- CSR build (sorted by src) ----
    hist_kernel<<<NSB, blk, 0, stream>>>(src, hist_part);
    colscan_kernel<<<N_UE / 256, blk, 0, stream>>>(hist_part, base_mat, cnt);
    scan_kernel<<<1, blk, 0, stream>>>(cnt, offs);
    scatter_kernel<<<NSB, blk, 0, stream>>>(src, dst, e0ua, e0au, base_mat, offs,
                                            dst_s, eAB, perm);

    init_kernel<<<N_UE * 32 / 256, blk, 0, stream>>>(x_ue, Wm1_ua, bm1_ua, bm1_au, Qua, Pau);

    // ---- layer 1: messages + aggregation ----
    seg_edge_kernel<false, true, false><<<EGRID, blk, 0, stream>>>(
        offs, dst_s, eAB, perm, nullptr, nullptr, nullptr, nullptr,
        nullptr, nullptr, Qua, Pau, Wm1_ua + 32, Wm1_au,
        agg_ue, partial, nullptr, nullptr);
    node_ue_kernel<true, false><<<N_UE / 256, blk, 0, stream>>>(
        x_ue, agg_ue, Wu1_ue, bu1_ue, Wm_ua, bm_ua, We1_ua, We1_au,
        nullptr, nullptr, nullptr, nullptr,
        x_ueA, Qua, RueA, RueB, nullptr);
    node_ap_kernel<true, false><<<N_AP, blk, 0, stream>>>(
        partial, nullptr, Wu1_ap, bu1_ap, Wm_au, bm_au,
        We1_ua + 64, be1_ua, We1_au + 64, be1_au,
        x_apA, Pau, RapA, RapB);

    // ---- edge-update 1 fused with layer-2 messages ----
    seg_edge_kernel<true, true, false><<<EGRID, blk, 0, stream>>>(
        offs, dst_s, eAB, perm, RueA, RueB, RapA, RapB,
        We1_ua + 128, We1_au + 128, Qua, Pau, Wm_ua + 1024, Wm_au + 1024,
        agg_ue, partial, nullptr, nullptr);
    node_ue_kernel<false, false><<<N_UE / 256, blk, 0, stream>>>(
        x_ueA, agg_ue, Wu_ue, bu_ue, Wm_ua + 1088, bm_ua + 32, We_ua, We_au,
        nullptr, nullptr, nullptr, nullptr,
        x_ueB, Qua, RueA, RueB, nullptr);
    node_ap_kernel<false, false><<<N_AP, blk, 0, stream>>>(
        partial, x_apA, Wu_ap, bu_ap, Wm_au + 1088, bm_au + 32,
        We_ua + 64, be_ua, We_au + 64, be_au,
        x_apB, Pau, RapA, RapB);

    // ---- edge-update 2 fused with layer-3 messages ----
    seg_edge_kernel<true, true, false><<<EGRID, blk, 0, stream>>>(
        offs, dst_s, eAB, perm, RueA, RueB, RapA, RapB,
        We_ua + 128, We_au + 128, Qua, Pau, Wm_ua + 2112, Wm_au + 2112,
        agg_ue, partial, nullptr, nullptr);
    node_ue_kernel<false, false><<<N_UE / 256, blk, 0, stream>>>(
        x_ueB, agg_ue, Wu_ue + 2048, bu_ue + 32, Wm_ua + 2176, bm_ua + 64,
        We_ua + 132, We_au + 132,
        nullptr, nullptr, nullptr, nullptr,
        x_ueA, Qua, RueA, RueB, nullptr);
    node_ap_kernel<false, false><<<N_AP, blk, 0, stream>>>(
        partial, x_apB, Wu_ap + 2048, bu_ap + 32, Wm_au + 2176, bm_au + 64,
        We_ua + 196, be_ua + 2, We_au + 196, be_au + 2,
        x_apA, Pau, RapA, RapB);

    // ---- edge-update 3 fused with layer-4 messages ----
    seg_edge_kernel<true, true, false><<<EGRID, blk, 0, stream>>>(
        offs, dst_s, eAB, perm, RueA, RueB, RapA, RapB,
        We_ua + 260, We_au + 260, Qua, Pau, Wm_ua + 3200, Wm_au + 3200,
        agg_ue, partial, nullptr, nullptr);
    node_ue_kernel<false, true><<<N_UE / 256, blk, 0, stream>>>(
        x_ueA, agg_ue, Wu_ue + 4096, bu_ue + 64, nullptr, nullptr,
        We_ua + 264, We_au + 264,
        Wp1, bp1, Wp2, bp2,
        x_ueB, nullptr, RueA, RueB, out_ue);
    node_ap_kernel<false, true><<<N_AP, blk, 0, stream>>>(
        partial, x_apA, Wu_ap + 4096, bu_ap + 64, nullptr, nullptr,
        We_ua + 328, be_ua + 4, We_au + 328, be_au + 4,
        out_ap, nullptr, RapA, RapB);

    // ---- final edge update (layer 4), scatter to original order ----
    seg_edge_kernel<true, false, true><<<EGRID, blk, 0, stream>>>(
        offs, dst_s, eAB, perm, RueA, RueB, RapA, RapB,
        We_ua + 392, We_au + 392, nullptr, nullptr, nullptr, nullptr,
        nullptr, nullptr, out_eua, out_eau);
}

// Round 3
// 1823.225 us; speedup vs baseline: 1.0660x; 1.0660x over previous
//
#include <hip/hip_runtime.h>
#include <math.h>

#define N_UE 16384
#define N_AP 128
#define NE   2097152
#define EGRID 1024      // edge blocks; each owns CHUNK edges; must equal NPART
#define NPART 1024
#define CHUNK 2048
#define STAGE 512
#define NSTG  (CHUNK / STAGE)
#define SLICE (STAGE / 8)   // 64 edges per 32-lane group per stage
#define NSB   256           // sort blocks
#define EPSB  (NE / NSB)

// ---------------------------------------------------------------------------
// init: Qua1[u][d] = x_ue[u]*Wm1_ua[0][d] + bm1_ua[d];  Pau1[a][d] = bm1_au[d]
// ---------------------------------------------------------------------------
__global__ __launch_bounds__(256) void init_kernel(
    const float* __restrict__ x_ue, const float* __restrict__ Wm1_ua,
    const float* __restrict__ bm1_ua, const float* __restrict__ bm1_au,
    float* __restrict__ Qua, float* __restrict__ Pau)
{
    int i = blockIdx.x * 256 + threadIdx.x;   // grid covers N_UE*32 exactly
    int d = i & 31;
    Qua[i] = fmaf(x_ue[i >> 5], Wm1_ua[d], bm1_ua[d]);
    if (i < N_AP * 32) Pau[i] = bm1_au[d];
}

// ---------------------------------------------------------------------------
// CSR build: histogram -> column scan -> prefix scan -> scatter
// ---------------------------------------------------------------------------
__global__ __launch_bounds__(256) void hist_kernel(
    const int* __restrict__ src, int* __restrict__ hist_part)
{
    __shared__ int h[N_UE];
    for (int i = threadIdx.x; i < N_UE; i += 256) h[i] = 0;
    __syncthreads();
    const int b = blockIdx.x, beg = b * EPSB;
    for (int e = beg + threadIdx.x; e < beg + EPSB; e += 256)
        atomicAdd(&h[src[e]], 1);
    __syncthreads();
    for (int i = threadIdx.x; i < N_UE; i += 256) hist_part[b * N_UE + i] = h[i];
}

__global__ __launch_bounds__(256) void colscan_kernel(
    const int* __restrict__ hist_part, int* __restrict__ base, int* __restrict__ cnt)
{
    const int u = blockIdx.x * 256 + threadIdx.x;   // grid = N_UE/256
    int run = 0;
    for (int b = 0; b < NSB; ++b) {
        int t = hist_part[b * N_UE + u];
        base[b * N_UE + u] = run;
        run += t;
    }
    cnt[u] = run;
}

__global__ __launch_bounds__(256) void scan_kernel(
    const int* __restrict__ cnt, int* __restrict__ offs)
{
    __shared__ int ps[256];
    __shared__ int ps2[257];
    const int t = threadIdx.x;
    const int b0 = t * (N_UE / 256);
    int s = 0;
    for (int i = 0; i < N_UE / 256; ++i) s += cnt[b0 + i];
    ps[t] = s;
    __syncthreads();
    if (t == 0) {
        int r = 0;
        for (int i = 0; i < 256; ++i) { ps2[i] = r; r += ps[i]; }
        ps2[256] = r;
    }
    __syncthreads();
    int r = ps2[t];
    for (int i = 0; i < N_UE / 256; ++i) { offs[b0 + i] = r; r += cnt[b0 + i]; }
    if (t == 255) offs[N_UE] = ps2[256];
}

__global__ __launch_bounds__(256) void scatter_kernel(
    const int* __restrict__ src, const int* __restrict__ dst,
    const float2* __restrict__ e0ua, const float2* __restrict__ e0au,
    const int* __restrict__ base, const int* __restrict__ offs,
    int2* __restrict__ sd, float4* __restrict__ eAB, int* __restrict__ perm)
{
    __shared__ int cursor[N_UE];
    const int b = blockIdx.x;
    for (int i = threadIdx.x; i < N_UE; i += 256)
        cursor[i] = offs[i] + base[b * N_UE + i];
    __syncthreads();
    const int beg = b * EPSB;
    for (int e = beg + threadIdx.x; e < beg + EPSB; e += 256) {
        int s = src[e];
        int pos = atomicAdd(&cursor[s], 1);
        sd[pos] = make_int2(s, dst[e]);
        float2 a = e0ua[e], c = e0au[e];
        eAB[pos] = make_float4(a.x, a.y, c.x, c.y);
        perm[pos] = e;
    }
}

// ---------------------------------------------------------------------------
// Chunked fused edge kernel: block owns CHUNK contiguous sorted edges.
// Per stage of 512 edges: coalesced load -> (EUPD edge-parallel) -> MSG
// group-serial over LDS with register segment accumulation.
// ---------------------------------------------------------------------------
template<bool EUPD>
__global__ __launch_bounds__(256) void chunk_edge_kernel(
    const int2* __restrict__ sd, float4* __restrict__ eAB,
    const float2* __restrict__ RueA, const float2* __restrict__ RueB,
    const float2* __restrict__ RapA, const float2* __restrict__ RapB,
    const float* __restrict__ EcA, const float* __restrict__ EcB,
    const float* __restrict__ Qua, const float* __restrict__ Pau,
    const float* __restrict__ cu, const float* __restrict__ cw,
    float* __restrict__ agg_ue, float* __restrict__ partial_ap)
{
    __shared__ float aggap_s[N_AP * 32];     // 16 KB
    __shared__ int2   sd_s[STAGE];           // 4 KB
    __shared__ float4 eab_s[STAGE];          // 8 KB

    const int tid = threadIdx.x, lane = tid & 31, g = tid >> 5;

    const float u0 = cu[lane], u1 = cu[32 + lane];
    const float w0 = cw[lane], w1 = cw[32 + lane];
    for (int i = tid; i < N_AP * 32; i += 256) aggap_s[i] = 0.f;

    float c00 = 0.f, c01 = 0.f, c10 = 0.f, c11 = 0.f;
    float d00 = 0.f, d01 = 0.f, d10 = 0.f, d11 = 0.f;
    if constexpr (EUPD) {
        c00 = EcA[0]; c01 = EcA[1]; c10 = EcA[2]; c11 = EcA[3];
        d00 = EcB[0]; d01 = EcB[1]; d10 = EcB[2]; d11 = EcB[3];
    }

    const int base0 = blockIdx.x * CHUNK;

    for (int stg = 0; stg < NSTG; ++stg) {
        const int base = base0 + stg * STAGE;
        __syncthreads();   // stage buffers free (prev round's readers done)
        for (int k = tid; k < STAGE; k += 256) {
            sd_s[k]  = sd[base + k];
            eab_s[k] = eAB[base + k];
        }
        __syncthreads();
        if constexpr (EUPD) {
            for (int k = tid; k < STAGE; k += 256) {
                int2 s2 = sd_s[k];
                float4 e4 = eab_s[k];
                float2 ru = RueA[s2.x], ra = RapA[s2.y];
                float n0 = fmaxf(ru.x + ra.x + e4.x * c00 + e4.y * c10, 0.f);
                float n1 = fmaxf(ru.y + ra.y + e4.x * c01 + e4.y * c11, 0.f);
                float2 rv = RueB[s2.x], rb = RapB[s2.y];
                float m0 = fmaxf(rv.x + rb.x + e4.z * d00 + e4.w * d10, 0.f);
                float m1 = fmaxf(rv.y + rb.y + e4.z * d01 + e4.w * d11, 0.f);
                float4 ne = make_float4(n0, n1, m0, m1);
                eab_s[k] = ne;
                eAB[base + k] = ne;          // persist for next layer
            }
            __syncthreads();
        }
        // ---- MSG phase: group g walks slice [g*SLICE, (g+1)*SLICE) ----
        int cur = -1;
        float acc = 0.f, q = 0.f;
        const int j0 = g * SLICE;
        #pragma unroll 8
        for (int j = 0; j < SLICE; ++j) {
            int2 s2 = sd_s[j0 + j];          // broadcast ds_read
            float4 e4 = eab_s[j0 + j];       // broadcast ds_read_b128
            if (s2.x != cur) {
                if (cur >= 0) atomicAdd(&agg_ue[cur * 32 + lane], acc);
                acc = 0.f;
                cur = s2.x;
                q = Qua[cur * 32 + lane];    // coalesced 128B, L1-hot
            }
            float mua = fmaxf(fmaf(e4.x, u0, fmaf(e4.y, u1, q)), 0.f);
            atomicAdd(&aggap_s[s2.y * 32 + lane], mua);          // bank-clean
            float p = Pau[s2.y * 32 + lane];                     // L1-hot 16KB
            float mau = fmaxf(fmaf(e4.z, w0, fmaf(e4.w, w1, p)), 0.f);
            acc += mau;
        }
        if (cur >= 0) atomicAdd(&agg_ue[cur * 32 + lane], acc);
    }
    __syncthreads();
    float* outp = partial_ap + (size_t)blockIdx.x * (N_AP * 32);
    for (int i = tid; i < N_AP * 32; i += 256) outp[i] = aggap_s[i];
}

// ---------------------------------------------------------------------------
// Final edge update (layer 4): pure edge-parallel, scatter to original order.
// ---------------------------------------------------------------------------
__global__ __launch_bounds__(256) void final_edge_kernel(
    const int2* __restrict__ sd, const float4* __restrict__ eAB,
    const int* __restrict__ perm,
    const float2* __restrict__ RueA, const float2* __restrict__ RueB,
    const float2* __restrict__ RapA, const float2* __restrict__ RapB,
    const float* __restrict__ EcA, const float* __restrict__ EcB,
    float2* __restrict__ out_eua, float2* __restrict__ out_eau)
{
    const int e = blockIdx.x * 256 + threadIdx.x;   // grid = NE/256
    int2 s2 = sd[e];
    float4 e4 = eAB[e];
    float c00 = EcA[0], c01 = EcA[1], c10 = EcA[2], c11 = EcA[3];
    float d00 = EcB[0], d01 = EcB[1], d10 = EcB[2], d11 = EcB[3];
    float2 ru = RueA[s2.x], ra = RapA[s2.y];
    float n0 = fmaxf(ru.x + ra.x + e4.x * c00 + e4.y * c10, 0.f);
    float n1 = fmaxf(ru.y + ra.y + e4.x * c01 + e4.y * c11, 0.f);
    float2 rv = RueB[s2.x], rb = RapB[s2.y];
    float m0 = fmaxf(rv.x + rb.x + e4.z * d00 + e4.w * d10, 0.f);
    float m1 = fmaxf(rv.y + rb.y + e4.z * d01 + e4.w * d11, 0.f);
    int p = perm[e];
    out_eua[p] = make_float2(n0, n1);
    out_eau[p] = make_float2(m0, m1);
}

// ---------------------------------------------------------------------------
// UE node update + next-layer tables (+ power head for LAST)
// ---------------------------------------------------------------------------
template<bool FIRST, bool LAST>
__global__ __launch_bounds__(256) void node_ue_kernel(
    const float* __restrict__ x_prev, const float* __restrict__ agg_ue,
    const float* __restrict__ Wu, const float* __restrict__ bu,
    const float* __restrict__ Wm_next, const float* __restrict__ bm_next,
    const float* __restrict__ WeUa, const float* __restrict__ WeUb,
    const float* __restrict__ Wp1, const float* __restrict__ bp1,
    const float* __restrict__ Wp2, const float* __restrict__ bp2,
    float* __restrict__ x_new, float* __restrict__ Qua_next,
    float2* __restrict__ RueA, float2* __restrict__ RueB,
    float2* __restrict__ ue_out)
{
    constexpr int KIN = FIRST ? 33 : 64;
    __shared__ float Wu_s[64 * 32];
    __shared__ float Wm_s[32 * 32];
    __shared__ float WeA_s[64], WeB_s[64];
    __shared__ float bu_s[32], bm_s[32];
    __shared__ float Wp1_s[32 * 16], bp1_s[16], Wp2_s[16];

    const int tid = threadIdx.x;
    for (int i = tid; i < KIN * 32; i += 256) Wu_s[i] = Wu[i];
    if (tid < 32) bu_s[tid] = bu[tid];
    if (!LAST) {
        for (int i = tid; i < 1024; i += 256) Wm_s[i] = Wm_next[i];
        if (tid < 32) bm_s[tid] = bm_next[tid];
    }
    if (tid < 64) { WeA_s[tid] = WeUa[tid]; WeB_s[tid] = WeUb[tid]; }
    if (LAST) {
        for (int i = tid; i < 512; i += 256) Wp1_s[i] = Wp1[i];
        if (tid < 16) { bp1_s[tid] = bp1[tid]; Wp2_s[tid] = Wp2[tid]; }
    }
    __syncthreads();

    const int u = blockIdx.x * 256 + tid;
    float in[KIN];
    if (FIRST) {
        in[0] = x_prev[u];
        #pragma unroll
        for (int k = 0; k < 32; ++k) in[1 + k] = agg_ue[u * 32 + k];
    } else {
        #pragma unroll
        for (int k = 0; k < 32; ++k) in[k] = x_prev[u * 32 + k];
        #pragma unroll
        for (int k = 0; k < 32; ++k) in[32 + k] = agg_ue[u * 32 + k];
    }
    float out[32];
    #pragma unroll
    for (int d = 0; d < 32; ++d) {
        float acc = bu_s[d];
        #pragma unroll
        for (int k = 0; k < KIN; ++k) acc = fmaf(in[k], Wu_s[k * 32 + d], acc);
        out[d] = fmaxf(acc, 0.f);
    }
    #pragma unroll
    for (int d = 0; d < 32; ++d) x_new[u * 32 + d] = out[d];
    if (!LAST) {
        #pragma unroll
        for (int d = 0; d < 32; ++d) {
            float acc = bm_s[d];
            #pragma unroll
            for (int k = 0; k < 32; ++k) acc = fmaf(out[k], Wm_s[k * 32 + d], acc);
            Qua_next[u * 32 + d] = acc;
        }
    }
    float r0 = 0.f, r1 = 0.f, s0 = 0.f, s1 = 0.f;
    #pragma unroll
    for (int k = 0; k < 32; ++k) {
        r0 = fmaf(out[k], WeA_s[k * 2],     r0);
        r1 = fmaf(out[k], WeA_s[k * 2 + 1], r1);
        s0 = fmaf(out[k], WeB_s[k * 2],     s0);
        s1 = fmaf(out[k], WeB_s[k * 2 + 1], s1);
    }
    RueA[u] = make_float2(r0, r1);
    RueB[u] = make_float2(s0, s1);
    if (LAST) {
        float z = bp2[0];
        #pragma unroll
        for (int j = 0; j < 16; ++j) {
            float h = bp1_s[j];
            #pragma unroll
            for (int k = 0; k < 32; ++k) h = fmaf(out[k], Wp1_s[k * 16 + j], h);
            z = fmaf(fmaxf(h, 0.f), Wp2_s[j], z);
        }
        float pw = 1.f / (1.f + expf(-z));
        ue_out[u] = make_float2(out[0], pw);
    }
}

// ---------------------------------------------------------------------------
// AP: reduce partials -> agg_ap, node update, next-layer tables
// ---------------------------------------------------------------------------
template<bool FIRST, bool LAST>
__global__ __launch_bounds__(256) void node_ap_kernel(
    const float* __restrict__ partial,
    const float* __restrict__ x_prev,
    const float* __restrict__ Wu, const float* __restrict__ bu,
    const float* __restrict__ Wm_next, const float* __restrict__ bm_next,
    const float* __restrict__ WeA, const float* __restrict__ beA,
    const float* __restrict__ WeB, const float* __restrict__ beB,
    float* __restrict__ x_new, float* __restrict__ Pau_next,
    float2* __restrict__ RapA, float2* __restrict__ RapB)
{
    __shared__ float red[256];
    __shared__ float agg_s[32];
    __shared__ float xnew_s[32];
    const int a = blockIdx.x, tid = threadIdx.x;
    const int d = tid & 31, p0 = tid >> 5;
    float acc = 0.f;
    for (int p = p0; p < NPART; p += 8)
        acc += partial[(size_t)p * (N_AP * 32) + a * 32 + d];
    red[tid] = acc;
    __syncthreads();
    if (tid < 32) {
        float s = 0.f;
        #pragma unroll
        for (int i = 0; i < 8; ++i) s += red[i * 32 + tid];
        agg_s[tid] = s;
    }
    __syncthreads();
    if (tid < 32) {
        float acc2 = bu[d];
        if (FIRST) {
            #pragma unroll
            for (int k = 0; k < 32; ++k) acc2 = fmaf(agg_s[k], Wu[k * 32 + d], acc2);
        } else {
            #pragma unroll
            for (int k = 0; k < 32; ++k) acc2 = fmaf(x_prev[a * 32 + k], Wu[k * 32 + d], acc2);
            #pragma unroll
            for (int k = 0; k < 32; ++k) acc2 = fmaf(agg_s[k], Wu[(32 + k) * 32 + d], acc2);
        }
        float xn = fmaxf(acc2, 0.f);
        xnew_s[d] = xn;
        x_new[a * 32 + d] = xn;
    }
    __syncthreads();
    if (!LAST) {
        if (tid < 32) {
            float acc3 = bm_next[d];
            #pragma unroll
            for (int k = 0; k < 32; ++k) acc3 = fmaf(xnew_s[k], Wm_next[k * 32 + d], acc3);
            Pau_next[a * 32 + d] = acc3;
        }
    }
    if (tid == 0) {
        float q0 = beA[0], q1 = beA[1], t0 = beB[0], t1 = beB[1];
        #pragma unroll
        for (int k = 0; k < 32; ++k) {
            q0 = fmaf(xnew_s[k], WeA[k * 2],     q0);
            q1 = fmaf(xnew_s[k], WeA[k * 2 + 1], q1);
            t0 = fmaf(xnew_s[k], WeB[k * 2],     t0);
            t1 = fmaf(xnew_s[k], WeB[k * 2 + 1], t1);
        }
        RapA[a] = make_float2(q0, q1);
        RapB[a] = make_float2(t0, t1);
    }
}

// ---------------------------------------------------------------------------
extern "C" void kernel_launch(void* const* d_in, const int* in_sizes, int n_in,
                              void* d_out_v, int out_size, void* d_ws, size_t ws_size,
                              hipStream_t stream)
{
    const float*  x_ue   = (const float*)d_in[0];
    const float2* e0ua   = (const float2*)d_in[1];
    const float2* e0au   = (const float2*)d_in[2];
    const int*    src    = (const int*)d_in[3];
    const int*    dst    = (const int*)d_in[4];
    const float* Wm1_ua = (const float*)d_in[5];
    const float* bm1_ua = (const float*)d_in[6];
    const float* Wm1_au = (const float*)d_in[7];
    const float* bm1_au = (const float*)d_in[8];
    const float* Wu1_ap = (const float*)d_in[9];
    const float* bu1_ap = (const float*)d_in[10];
    const float* Wu1_ue = (const float*)d_in[11];
    const float* bu1_ue = (const float*)d_in[12];
    const float* We1_ua = (const float*)d_in[13];
    const float* be1_ua = (const float*)d_in[14];
    const float* We1_au = (const float*)d_in[15];
    const float* be1_au = (const float*)d_in[16];
    const float* Wm_ua  = (const float*)d_in[17];
    const float* bm_ua  = (const float*)d_in[18];
    const float* Wm_au  = (const float*)d_in[19];
    const float* bm_au  = (const float*)d_in[20];
    const float* Wu_ap  = (const float*)d_in[21];
    const float* bu_ap  = (const float*)d_in[22];
    const float* Wu_ue  = (const float*)d_in[23];
    const float* bu_ue  = (const float*)d_in[24];
    const float* We_ua  = (const float*)d_in[25];
    const float* be_ua  = (const float*)d_in[26];
    const float* We_au  = (const float*)d_in[27];
    const float* be_au  = (const float*)d_in[28];
    const float* Wp1    = (const float*)d_in[29];
    const float* bp1    = (const float*)d_in[30];
    const float* Wp2    = (const float*)d_in[31];
    const float* bp2    = (const float*)d_in[32];

    float*  outp    = (float*)d_out_v;
    float2* out_ue  = (float2*)outp;                              // [16384][2]
    float*  out_ap  = outp + N_UE * 2;                            // [128][32]
    float2* out_eua = (float2*)(outp + N_UE * 2 + N_AP * 32);     // [E][2]
    float2* out_eau = (float2*)(outp + N_UE * 2 + N_AP * 32 + (size_t)NE * 2);

    float* ws = (float*)d_ws;
    float* x_ueA  = ws;          ws += N_UE * 32;
    float* x_ueB  = ws;          ws += N_UE * 32;
    float* x_apA  = ws;          ws += N_AP * 32;
    float* x_apB  = ws;          ws += N_AP * 32;
    float* agg_ue = ws;          ws += N_UE * 32;
    float* Qua    = ws;          ws += N_UE * 32;
    float* Pau    = ws;          ws += N_AP * 32;
    float2* RueA  = (float2*)ws; ws += N_UE * 2;
    float2* RueB  = (float2*)ws; ws += N_UE * 2;
    float2* RapA  = (float2*)ws; ws += N_AP * 2;
    float2* RapB  = (float2*)ws; ws += N_AP * 2;
    float* partial = ws;         ws += (size_t)NPART * N_AP * 32; // 16 MB
    int* base_mat  = (int*)partial;                               // alias (consumed pre-MSG)
    int2* sd   = (int2*)ws;      ws += (size_t)NE * 2;            // 16 MB
    int* perm  = (int*)ws;       ws += NE;                        // 8 MB
    int* cnt   = (int*)ws;       ws += N_UE;
    int* offs  = (int*)ws;       ws += N_UE + 1;
    float4* eAB = (float4*)ws;   ws += (size_t)NE * 4;            // 32 MB
    int* hist_part = (int*)eAB;                                   // alias (consumed pre-scatter)

    dim3 blk(256);
    const size_t aggBytes = (size_t)N_UE * 32 * sizeof(float);

    // ---- CSR build (sorted by src) ----
    hist_kernel<<<NSB, blk, 0, stream>>>(src, hist_part);
    colscan_kernel<<<N_UE / 256, blk, 0, stream>>>(hist_part, base_mat, cnt);
    scan_kernel<<<1, blk, 0, stream>>>(cnt, offs);
    scatter_kernel<<<NSB, blk, 0, stream>>>(src, dst, e0ua, e0au, base_mat, offs,
                                            sd, eAB, perm);

    init_kernel<<<N_UE * 32 / 256, blk, 0, stream>>>(x_ue, Wm1_ua, bm1_ua, bm1_au, Qua, Pau);

    // ---- layer 1: messages + aggregation ----
    hipMemsetAsync(agg_ue, 0, aggBytes, stream);
    chunk_edge_kernel<false><<<EGRID, blk, 0, stream>>>(
        sd, eAB, nullptr, nullptr, nullptr, nullptr, nullptr, nullptr,
        Qua, Pau, Wm1_ua + 32, Wm1_au, agg_ue, partial);
    node_ue_kernel<true, false><<<N_UE / 256, blk, 0, stream>>>(
        x_ue, agg_ue, Wu1_ue, bu1_ue, Wm_ua, bm_ua, We1_ua, We1_au,
        nullptr, nullptr, nullptr, nullptr,
        x_ueA, Qua, RueA, RueB, nullptr);
    node_ap_kernel<true, false><<<N_AP, blk, 0, stream>>>(
        partial, nullptr, Wu1_ap, bu1_ap, Wm_au, bm_au,
        We1_ua + 64, be1_ua, We1_au + 64, be1_au,
        x_apA, Pau, RapA, RapB);

    // ---- edge-update 1 fused with layer-2 messages ----
    hipMemsetAsync(agg_ue, 0, aggBytes, stream);
    chunk_edge_kernel<true><<<EGRID, blk, 0, stream>>>(
        sd, eAB, RueA, RueB, RapA, RapB, We1_ua + 128, We1_au + 128,
        Qua, Pau, Wm_ua + 1024, Wm_au + 1024, agg_ue, partial);
    node_ue_kernel<false, false><<<N_UE / 256, blk, 0, stream>>>(
        x_ueA, agg_ue, Wu_ue, bu_ue, Wm_ua + 1088, bm_ua + 32, We_ua, We_au,
        nullptr, nullptr, nullptr, nullptr,
        x_ueB, Qua, RueA, RueB, nullptr);
    node_ap_kernel<false, false><<<N_AP, blk, 0, stream>>>(
        partial, x_apA, Wu_ap, bu_ap, Wm_au + 1088, bm_au + 32,
        We_ua + 64, be_ua, We_au + 64, be_au,
        x_apB, Pau, RapA, RapB);

    // ---- edge-update 2 fused with layer-3 messages ----
    hipMemsetAsync(agg_ue, 0, aggBytes, stream);
    chunk_edge_kernel<true><<<EGRID, blk, 0, stream>>>(
        sd, eAB, RueA, RueB, RapA, RapB, We_ua + 128, We_au + 128,
        Qua, Pau, Wm_ua + 2112, Wm_au + 2112, agg_ue, partial);
    node_ue_kernel<false, false><<<N_UE / 256, blk, 0, stream>>>(
        x_ueB, agg_ue, Wu_ue + 2048, bu_ue + 32, Wm_ua + 2176, bm_ua + 64,
        We_ua + 132, We_au + 132,
        nullptr, nullptr, nullptr, nullptr,
        x_ueA, Qua, RueA, RueB, nullptr);
    node_ap_kernel<false, false><<<N_AP, blk, 0, stream>>>(
        partial, x_apB, Wu_ap + 2048, bu_ap + 32, Wm_au + 2176, bm_au + 64,
        We_ua + 196, be_ua + 2, We_au + 196, be_au + 2,
        x_apA, Pau, RapA, RapB);

    // ---- edge-update 3 fused with layer-4 messages ----
    hipMemsetAsync(agg_ue, 0, aggBytes, stream);
    chunk_edge_kernel<true><<<EGRID, blk, 0, stream>>>(
        sd, eAB, RueA, RueB, RapA, RapB, We_ua + 260, We_au + 260,
        Qua, Pau, Wm_ua + 3200, Wm_au + 3200, agg_ue, partial);
    node_ue_kernel<false, true><<<N_UE / 256, blk, 0, stream>>>(
        x_ueA, agg_ue, Wu_ue + 4096, bu_ue + 64, nullptr, nullptr,
        We_ua + 264, We_au + 264,
        Wp1, bp1, Wp2, bp2,
        x_ueB, nullptr, RueA, RueB, out_ue);
    node_ap_kernel<false, true><<<N_AP, blk, 0, stream>>>(
        partial, x_apA, Wu_ap + 4096, bu_ap + 64, nullptr, nullptr,
        We_ua + 328, be_ua + 4, We_au + 328, be_au + 4,
        out_ap, nullptr, RapA, RapB);

    // ---- final edge update (layer 4), scatter to original order ----
    final_edge_kernel<<<NE / 256, blk, 0, stream>>>(
        sd, eAB, perm, RueA, RueB, RapA, RapB,
        We_ua + 392, We_au + 392, out_eua, out_eau);
}

// Round 4
// 1357.173 us; speedup vs baseline: 1.4321x; 1.3434x over previous
//
#include <hip/hip_runtime.h>
#include <math.h>

#define N_UE 16384
#define N_AP 128
#define NE   2097152
#define NSB  256               // sort blocks
#define EPSB (NE / NSB)        // 8192 edges per sort block
#define KED  32                // edges per thread in pass kernels
#define NBLK (NE / (256 * KED))   // 256 blocks per pass
#define NPART NBLK             // 256 agg_ap partials

// ---------------------------------------------------------------------------
// init: Qua1[u][d] = x_ue[u]*Wm1_ua[0][d] + bm1_ua[d];  Pau1[a][d] = bm1_au[d]
// ---------------------------------------------------------------------------
__global__ __launch_bounds__(256) void init_kernel(
    const float* __restrict__ x_ue, const float* __restrict__ Wm1_ua,
    const float* __restrict__ bm1_ua, const float* __restrict__ bm1_au,
    float* __restrict__ Qua, float* __restrict__ Pau)
{
    int i = blockIdx.x * 256 + threadIdx.x;
    int d = i & 31;
    Qua[i] = fmaf(x_ue[i >> 5], Wm1_ua[d], bm1_ua[d]);
    if (i < N_AP * 32) Pau[i] = bm1_au[d];
}

// ---------------------------------------------------------------------------
// src-sort: histogram -> column scan -> prefix scan -> scatter
// ---------------------------------------------------------------------------
__global__ __launch_bounds__(256) void hist_src(
    const int* __restrict__ src, int* __restrict__ histS)
{
    __shared__ int h[N_UE];
    for (int i = threadIdx.x; i < N_UE; i += 256) h[i] = 0;
    __syncthreads();
    const int beg = blockIdx.x * EPSB;
    for (int e = beg + threadIdx.x; e < beg + EPSB; e += 256)
        atomicAdd(&h[src[e]], 1);
    __syncthreads();
    for (int i = threadIdx.x; i < N_UE; i += 256) histS[blockIdx.x * N_UE + i] = h[i];
}

__global__ __launch_bounds__(256) void colscan_kernel(
    const int* __restrict__ histS, int* __restrict__ baseS, int* __restrict__ cnt)
{
    const int u = blockIdx.x * 256 + threadIdx.x;
    int run = 0;
    for (int b = 0; b < NSB; ++b) {
        int t = histS[b * N_UE + u];
        baseS[b * N_UE + u] = run;
        run += t;
    }
    cnt[u] = run;
}

__global__ __launch_bounds__(256) void scan_kernel(
    const int* __restrict__ cnt, int* __restrict__ offs)
{
    __shared__ int ps[256];
    __shared__ int ps2[257];
    const int t = threadIdx.x;
    const int b0 = t * (N_UE / 256);
    int s = 0;
    for (int i = 0; i < N_UE / 256; ++i) s += cnt[b0 + i];
    ps[t] = s;
    __syncthreads();
    if (t == 0) {
        int r = 0;
        for (int i = 0; i < 256; ++i) { ps2[i] = r; r += ps[i]; }
        ps2[256] = r;
    }
    __syncthreads();
    int r = ps2[t];
    for (int i = 0; i < N_UE / 256; ++i) { offs[b0 + i] = r; r += cnt[b0 + i]; }
    if (t == 255) offs[N_UE] = ps2[256];
}

__global__ __launch_bounds__(256) void scatter_src(
    const int* __restrict__ src, const int* __restrict__ dst,
    const float2* __restrict__ e0au,
    const int* __restrict__ baseS, const int* __restrict__ offs,
    int4* __restrict__ packS, int* __restrict__ invS)
{
    __shared__ int cursor[N_UE];
    const int b = blockIdx.x;
    for (int i = threadIdx.x; i < N_UE; i += 256)
        cursor[i] = offs[i] + baseS[b * N_UE + i];
    __syncthreads();
    const int beg = b * EPSB;
    for (int e = beg + threadIdx.x; e < beg + EPSB; e += 256) {
        int s = src[e];
        int pos = atomicAdd(&cursor[s], 1);
        float2 a = e0au[e];
        packS[pos] = make_int4(s, dst[e], __float_as_int(a.x), __float_as_int(a.y));
        invS[e] = pos;
    }
}

// ---------------------------------------------------------------------------
// dst-sort (128 bins)
// ---------------------------------------------------------------------------
__global__ __launch_bounds__(256) void hist_dst(
    const int* __restrict__ dst, int* __restrict__ histD)
{
    __shared__ int h[N_AP];
    if (threadIdx.x < N_AP) h[threadIdx.x] = 0;
    __syncthreads();
    const int beg = blockIdx.x * EPSB;
    for (int e = beg + threadIdx.x; e < beg + EPSB; e += 256)
        atomicAdd(&h[dst[e]], 1);
    __syncthreads();
    if (threadIdx.x < N_AP) histD[blockIdx.x * N_AP + threadIdx.x] = h[threadIdx.x];
}

__global__ __launch_bounds__(128) void scan_dst(
    const int* __restrict__ histD, int* __restrict__ offsD)
{
    __shared__ int colTot[N_AP], colStart[N_AP];
    const int a = threadIdx.x;
    int run = 0;
    for (int b = 0; b < NSB; ++b) {
        offsD[b * N_AP + a] = run;
        run += histD[b * N_AP + a];
    }
    colTot[a] = run;
    __syncthreads();
    if (a == 0) {
        int r = 0;
        for (int i = 0; i < N_AP; ++i) { colStart[i] = r; r += colTot[i]; }
    }
    __syncthreads();
    const int st = colStart[a];
    for (int b = 0; b < NSB; ++b) offsD[b * N_AP + a] += st;
}

__global__ __launch_bounds__(256) void scatter_dst(
    const int* __restrict__ src, const int* __restrict__ dst,
    const float2* __restrict__ e0ua, const int* __restrict__ offsD,
    int4* __restrict__ packD, int* __restrict__ invD)
{
    __shared__ int cursor[N_AP];
    const int b = blockIdx.x;
    if (threadIdx.x < N_AP) cursor[threadIdx.x] = offsD[b * N_AP + threadIdx.x];
    __syncthreads();
    const int beg = b * EPSB;
    for (int e = beg + threadIdx.x; e < beg + EPSB; e += 256) {
        int dt = dst[e];
        int pos = atomicAdd(&cursor[dt], 1);
        float2 a = e0ua[e];
        packD[pos] = make_int4(dt, src[e], __float_as_int(a.x), __float_as_int(a.y));
        invD[e] = pos;
    }
}

// ---------------------------------------------------------------------------
// Fused edge pass. Blocks [0,NBLK): src-sorted pass (m_au -> agg_ue, EUPD e_au).
// Blocks [NBLK,2*NBLK): dst-sorted pass (m_ua -> agg_ap partials, EUPD e_ua).
// One thread = KED consecutive sorted edges; dims = 8 x float4 registers.
// ---------------------------------------------------------------------------
#define RFL(x) __int_as_float(__builtin_amdgcn_readfirstlane(__float_as_int(x)))

template<bool EUPD>
__global__ __launch_bounds__(256) void edge_pass(
    int4* __restrict__ packS, int4* __restrict__ packD,
    const float2* __restrict__ RueA, const float2* __restrict__ RueB,
    const float2* __restrict__ RapA, const float2* __restrict__ RapB,
    const float* __restrict__ EcA, const float* __restrict__ EcB,
    const float* __restrict__ Qua, const float* __restrict__ Pau,
    const float* __restrict__ cu, const float* __restrict__ cw,
    float* __restrict__ agg_ue, float* __restrict__ partial_ap)
{
    __shared__ float aggap_s[N_AP * 32];
    const int tid = threadIdx.x;
    float4 acc[8];
    #pragma unroll
    for (int q = 0; q < 8; ++q) acc[q] = make_float4(0.f, 0.f, 0.f, 0.f);

    if (blockIdx.x < NBLK) {
        // ---------------- src pass ----------------
        float w0v[32], w1v[32];
        #pragma unroll
        for (int d = 0; d < 32; ++d) { w0v[d] = RFL(cw[d]); w1v[d] = RFL(cw[32 + d]); }
        float d00 = 0.f, d01 = 0.f, d10 = 0.f, d11 = 0.f;
        if constexpr (EUPD) {
            d00 = RFL(EcB[0]); d01 = RFL(EcB[1]); d10 = RFL(EcB[2]); d11 = RFL(EcB[3]);
        }
        const float4* __restrict__ Pau4 = (const float4*)Pau;
        const int base = (blockIdx.x * 256 + tid) * KED;
        int cur = -1;
        float rbx = 0.f, rby = 0.f;
        #pragma unroll 4
        for (int j = 0; j < KED; ++j) {
            int4 p = packS[base + j];
            int s = p.x, dt = p.y;
            float e0 = __int_as_float(p.z), e1 = __int_as_float(p.w);
            if (s != cur) {
                if (cur >= 0) {
                    float* row = agg_ue + cur * 32;
                    #pragma unroll
                    for (int q = 0; q < 8; ++q) {
                        atomicAdd(row + q * 4 + 0, acc[q].x);
                        atomicAdd(row + q * 4 + 1, acc[q].y);
                        atomicAdd(row + q * 4 + 2, acc[q].z);
                        atomicAdd(row + q * 4 + 3, acc[q].w);
                        acc[q] = make_float4(0.f, 0.f, 0.f, 0.f);
                    }
                }
                cur = s;
                if constexpr (EUPD) { float2 r = RueB[s]; rbx = r.x; rby = r.y; }
            }
            if constexpr (EUPD) {
                float2 rp = RapB[dt];
                float n0 = fmaxf(rbx + rp.x + e0 * d00 + e1 * d10, 0.f);
                float n1 = fmaxf(rby + rp.y + e0 * d01 + e1 * d11, 0.f);
                ((float2*)packS)[(size_t)(base + j) * 2 + 1] = make_float2(n0, n1);
                e0 = n0; e1 = n1;
            }
            const float4* pr = Pau4 + dt * 8;
            #pragma unroll
            for (int q = 0; q < 8; ++q) {
                float4 pv = pr[q];
                acc[q].x += fmaxf(fmaf(e0, w0v[q*4+0], fmaf(e1, w1v[q*4+0], pv.x)), 0.f);
                acc[q].y += fmaxf(fmaf(e0, w0v[q*4+1], fmaf(e1, w1v[q*4+1], pv.y)), 0.f);
                acc[q].z += fmaxf(fmaf(e0, w0v[q*4+2], fmaf(e1, w1v[q*4+2], pv.z)), 0.f);
                acc[q].w += fmaxf(fmaf(e0, w0v[q*4+3], fmaf(e1, w1v[q*4+3], pv.w)), 0.f);
            }
        }
        if (cur >= 0) {
            float* row = agg_ue + cur * 32;
            #pragma unroll
            for (int q = 0; q < 8; ++q) {
                atomicAdd(row + q * 4 + 0, acc[q].x);
                atomicAdd(row + q * 4 + 1, acc[q].y);
                atomicAdd(row + q * 4 + 2, acc[q].z);
                atomicAdd(row + q * 4 + 3, acc[q].w);
            }
        }
    } else {
        // ---------------- dst pass ----------------
        for (int i = tid; i < N_AP * 32; i += 256) aggap_s[i] = 0.f;
        __syncthreads();
        float u0v[32], u1v[32];
        #pragma unroll
        for (int d = 0; d < 32; ++d) { u0v[d] = RFL(cu[d]); u1v[d] = RFL(cu[32 + d]); }
        float c00 = 0.f, c01 = 0.f, c10 = 0.f, c11 = 0.f;
        if constexpr (EUPD) {
            c00 = RFL(EcA[0]); c01 = RFL(EcA[1]); c10 = RFL(EcA[2]); c11 = RFL(EcA[3]);
        }
        const float4* __restrict__ Qua4 = (const float4*)Qua;
        const int base = ((blockIdx.x - NBLK) * 256 + tid) * KED;
        int cur = -1;
        float rax = 0.f, ray = 0.f;
        #pragma unroll 4
        for (int j = 0; j < KED; ++j) {
            int4 p = packD[base + j];
            int dt = p.x, s = p.y;
            float e0 = __int_as_float(p.z), e1 = __int_as_float(p.w);
            if (dt != cur) {
                if (cur >= 0) {
                    float* row = aggap_s + cur * 32;
                    #pragma unroll
                    for (int q = 0; q < 8; ++q) {
                        atomicAdd(row + q * 4 + 0, acc[q].x);
                        atomicAdd(row + q * 4 + 1, acc[q].y);
                        atomicAdd(row + q * 4 + 2, acc[q].z);
                        atomicAdd(row + q * 4 + 3, acc[q].w);
                        acc[q] = make_float4(0.f, 0.f, 0.f, 0.f);
                    }
                }
                cur = dt;
                if constexpr (EUPD) { float2 r = RapA[dt]; rax = r.x; ray = r.y; }
            }
            if constexpr (EUPD) {
                float2 ru = RueA[s];
                float n0 = fmaxf(rax + ru.x + e0 * c00 + e1 * c10, 0.f);
                float n1 = fmaxf(ray + ru.y + e0 * c01 + e1 * c11, 0.f);
                ((float2*)packD)[(size_t)(base + j) * 2 + 1] = make_float2(n0, n1);
                e0 = n0; e1 = n1;
            }
            const float4* qr = Qua4 + s * 8;
            #pragma unroll
            for (int q = 0; q < 8; ++q) {
                float4 qv = qr[q];
                acc[q].x += fmaxf(fmaf(e0, u0v[q*4+0], fmaf(e1, u1v[q*4+0], qv.x)), 0.f);
                acc[q].y += fmaxf(fmaf(e0, u0v[q*4+1], fmaf(e1, u1v[q*4+1], qv.y)), 0.f);
                acc[q].z += fmaxf(fmaf(e0, u0v[q*4+2], fmaf(e1, u1v[q*4+2], qv.z)), 0.f);
                acc[q].w += fmaxf(fmaf(e0, u0v[q*4+3], fmaf(e1, u1v[q*4+3], qv.w)), 0.f);
            }
        }
        if (cur >= 0) {
            float* row = aggap_s + cur * 32;
            #pragma unroll
            for (int q = 0; q < 8; ++q) {
                atomicAdd(row + q * 4 + 0, acc[q].x);
                atomicAdd(row + q * 4 + 1, acc[q].y);
                atomicAdd(row + q * 4 + 2, acc[q].z);
                atomicAdd(row + q * 4 + 3, acc[q].w);
            }
        }
        __syncthreads();
        float* outp = partial_ap + (size_t)(blockIdx.x - NBLK) * (N_AP * 32);
        for (int i = tid; i < N_AP * 32; i += 256) outp[i] = aggap_s[i];
    }
}

// ---------------------------------------------------------------------------
// Final layer-4 edge update for both edge types, original order (gather).
// ---------------------------------------------------------------------------
__global__ __launch_bounds__(256) void final_edge(
    const int4* __restrict__ packS, const int4* __restrict__ packD,
    const int* __restrict__ invS, const int* __restrict__ invD,
    const float2* __restrict__ RueA, const float2* __restrict__ RueB,
    const float2* __restrict__ RapA, const float2* __restrict__ RapB,
    const float* __restrict__ EcA, const float* __restrict__ EcB,
    float2* __restrict__ out_eua, float2* __restrict__ out_eau)
{
    const int e = blockIdx.x * 256 + threadIdx.x;
    float c00 = EcA[0], c01 = EcA[1], c10 = EcA[2], c11 = EcA[3];
    float d00 = EcB[0], d01 = EcB[1], d10 = EcB[2], d11 = EcB[3];
    int4 pS = packS[invS[e]];     // (src, dst, e_au)
    {
        float e0 = __int_as_float(pS.z), e1 = __int_as_float(pS.w);
        float2 ru = RueB[pS.x], rp = RapB[pS.y];
        float m0 = fmaxf(ru.x + rp.x + e0 * d00 + e1 * d10, 0.f);
        float m1 = fmaxf(ru.y + rp.y + e0 * d01 + e1 * d11, 0.f);
        out_eau[e] = make_float2(m0, m1);
    }
    int4 pD = packD[invD[e]];     // (dst, src, e_ua)
    {
        float e0 = __int_as_float(pD.z), e1 = __int_as_float(pD.w);
        float2 ra = RapA[pD.x], ru = RueA[pD.y];
        float n0 = fmaxf(ru.x + ra.x + e0 * c00 + e1 * c10, 0.f);
        float n1 = fmaxf(ru.y + ra.y + e0 * c01 + e1 * c11, 0.f);
        out_eua[e] = make_float2(n0, n1);
    }
}

// ---------------------------------------------------------------------------
// UE node update + next-layer tables (+ power head for LAST)
// ---------------------------------------------------------------------------
template<bool FIRST, bool LAST>
__global__ __launch_bounds__(256) void node_ue_kernel(
    const float* __restrict__ x_prev, const float* __restrict__ agg_ue,
    const float* __restrict__ Wu, const float* __restrict__ bu,
    const float* __restrict__ Wm_next, const float* __restrict__ bm_next,
    const float* __restrict__ WeUa, const float* __restrict__ WeUb,
    const float* __restrict__ Wp1, const float* __restrict__ bp1,
    const float* __restrict__ Wp2, const float* __restrict__ bp2,
    float* __restrict__ x_new, float* __restrict__ Qua_next,
    float2* __restrict__ RueA, float2* __restrict__ RueB,
    float2* __restrict__ ue_out)
{
    constexpr int KIN = FIRST ? 33 : 64;
    __shared__ float Wu_s[64 * 32];
    __shared__ float Wm_s[32 * 32];
    __shared__ float WeA_s[64], WeB_s[64];
    __shared__ float bu_s[32], bm_s[32];
    __shared__ float Wp1_s[32 * 16], bp1_s[16], Wp2_s[16];

    const int tid = threadIdx.x;
    for (int i = tid; i < KIN * 32; i += 256) Wu_s[i] = Wu[i];
    if (tid < 32) bu_s[tid] = bu[tid];
    if (!LAST) {
        for (int i = tid; i < 1024; i += 256) Wm_s[i] = Wm_next[i];
        if (tid < 32) bm_s[tid] = bm_next[tid];
    }
    if (tid < 64) { WeA_s[tid] = WeUa[tid]; WeB_s[tid] = WeUb[tid]; }
    if (LAST) {
        for (int i = tid; i < 512; i += 256) Wp1_s[i] = Wp1[i];
        if (tid < 16) { bp1_s[tid] = bp1[tid]; Wp2_s[tid] = Wp2[tid]; }
    }
    __syncthreads();

    const int u = blockIdx.x * 256 + tid;
    float in[KIN];
    if (FIRST) {
        in[0] = x_prev[u];
        #pragma unroll
        for (int k = 0; k < 32; ++k) in[1 + k] = agg_ue[u * 32 + k];
    } else {
        #pragma unroll
        for (int k = 0; k < 32; ++k) in[k] = x_prev[u * 32 + k];
        #pragma unroll
        for (int k = 0; k < 32; ++k) in[32 + k] = agg_ue[u * 32 + k];
    }
    float out[32];
    #pragma unroll
    for (int d = 0; d < 32; ++d) {
        float acc = bu_s[d];
        #pragma unroll
        for (int k = 0; k < KIN; ++k) acc = fmaf(in[k], Wu_s[k * 32 + d], acc);
        out[d] = fmaxf(acc, 0.f);
    }
    #pragma unroll
    for (int d = 0; d < 32; ++d) x_new[u * 32 + d] = out[d];
    if (!LAST) {
        #pragma unroll
        for (int d = 0; d < 32; ++d) {
            float acc = bm_s[d];
            #pragma unroll
            for (int k = 0; k < 32; ++k) acc = fmaf(out[k], Wm_s[k * 32 + d], acc);
            Qua_next[u * 32 + d] = acc;
        }
    }
    float r0 = 0.f, r1 = 0.f, s0 = 0.f, s1 = 0.f;
    #pragma unroll
    for (int k = 0; k < 32; ++k) {
        r0 = fmaf(out[k], WeA_s[k * 2],     r0);
        r1 = fmaf(out[k], WeA_s[k * 2 + 1], r1);
        s0 = fmaf(out[k], WeB_s[k * 2],     s0);
        s1 = fmaf(out[k], WeB_s[k * 2 + 1], s1);
    }
    RueA[u] = make_float2(r0, r1);
    RueB[u] = make_float2(s0, s1);
    if (LAST) {
        float z = bp2[0];
        #pragma unroll
        for (int j = 0; j < 16; ++j) {
            float h = bp1_s[j];
            #pragma unroll
            for (int k = 0; k < 32; ++k) h = fmaf(out[k], Wp1_s[k * 16 + j], h);
            z = fmaf(fmaxf(h, 0.f), Wp2_s[j], z);
        }
        float pw = 1.f / (1.f + expf(-z));
        ue_out[u] = make_float2(out[0], pw);
    }
}

// ---------------------------------------------------------------------------
// AP: reduce partials -> agg_ap, node update, next-layer tables
// ---------------------------------------------------------------------------
template<bool FIRST, bool LAST>
__global__ __launch_bounds__(256) void node_ap_kernel(
    const float* __restrict__ partial,
    const float* __restrict__ x_prev,
    const float* __restrict__ Wu, const float* __restrict__ bu,
    const float* __restrict__ Wm_next, const float* __restrict__ bm_next,
    const float* __restrict__ WeA, const float* __restrict__ beA,
    const float* __restrict__ WeB, const float* __restrict__ beB,
    float* __restrict__ x_new, float* __restrict__ Pau_next,
    float2* __restrict__ RapA, float2* __restrict__ RapB)
{
    __shared__ float red[256];
    __shared__ float agg_s[32];
    __shared__ float xnew_s[32];
    const int a = blockIdx.x, tid = threadIdx.x;
    const int d = tid & 31, p0 = tid >> 5;
    float acc = 0.f;
    for (int p = p0; p < NPART; p += 8)
        acc += partial[(size_t)p * (N_AP * 32) + a * 32 + d];
    red[tid] = acc;
    __syncthreads();
    if (tid < 32) {
        float s = 0.f;
        #pragma unroll
        for (int i = 0; i < 8; ++i) s += red[i * 32 + tid];
        agg_s[tid] = s;
    }
    __syncthreads();
    if (tid < 32) {
        float acc2 = bu[d];
        if (FIRST) {
            #pragma unroll
            for (int k = 0; k < 32; ++k) acc2 = fmaf(agg_s[k], Wu[k * 32 + d], acc2);
        } else {
            #pragma unroll
            for (int k = 0; k < 32; ++k) acc2 = fmaf(x_prev[a * 32 + k], Wu[k * 32 + d], acc2);
            #pragma unroll
            for (int k = 0; k < 32; ++k) acc2 = fmaf(agg_s[k], Wu[(32 + k) * 32 + d], acc2);
        }
        float xn = fmaxf(acc2, 0.f);
        xnew_s[d] = xn;
        x_new[a * 32 + d] = xn;
    }
    __syncthreads();
    if (!LAST) {
        if (tid < 32) {
            float acc3 = bm_next[d];
            #pragma unroll
            for (int k = 0; k < 32; ++k) acc3 = fmaf(xnew_s[k], Wm_next[k * 32 + d], acc3);
            Pau_next[a * 32 + d] = acc3;
        }
    }
    if (tid == 0) {
        float q0 = beA[0], q1 = beA[1], t0 = beB[0], t1 = beB[1];
        #pragma unroll
        for (int k = 0; k < 32; ++k) {
            q0 = fmaf(xnew_s[k], WeA[k * 2],     q0);
            q1 = fmaf(xnew_s[k], WeA[k * 2 + 1], q1);
            t0 = fmaf(xnew_s[k], WeB[k * 2],     t0);
            t1 = fmaf(xnew_s[k], WeB[k * 2 + 1], t1);
        }
        RapA[a] = make_float2(q0, q1);
        RapB[a] = make_float2(t0, t1);
    }
}

// ---------------------------------------------------------------------------
extern "C" void kernel_launch(void* const* d_in, const int* in_sizes, int n_in,
                              void* d_out_v, int out_size, void* d_ws, size_t ws_size,
                              hipStream_t stream)
{
    const float*  x_ue   = (const float*)d_in[0];
    const float2* e0ua   = (const float2*)d_in[1];
    const float2* e0au   = (const float2*)d_in[2];
    const int*    src    = (const int*)d_in[3];
    const int*    dst    = (const int*)d_in[4];
    const float* Wm1_ua = (const float*)d_in[5];
    const float* bm1_ua = (const float*)d_in[6];
    const float* Wm1_au = (const float*)d_in[7];
    const float* bm1_au = (const float*)d_in[8];
    const float* Wu1_ap = (const float*)d_in[9];
    const float* bu1_ap = (const float*)d_in[10];
    const float* Wu1_ue = (const float*)d_in[11];
    const float* bu1_ue = (const float*)d_in[12];
    const float* We1_ua = (const float*)d_in[13];
    const float* be1_ua = (const float*)d_in[14];
    const float* We1_au = (const float*)d_in[15];
    const float* be1_au = (const float*)d_in[16];
    const float* Wm_ua  = (const float*)d_in[17];
    const float* bm_ua  = (const float*)d_in[18];
    const float* Wm_au  = (const float*)d_in[19];
    const float* bm_au  = (const float*)d_in[20];
    const float* Wu_ap  = (const float*)d_in[21];
    const float* bu_ap  = (const float*)d_in[22];
    const float* Wu_ue  = (const float*)d_in[23];
    const float* bu_ue  = (const float*)d_in[24];
    const float* We_ua  = (const float*)d_in[25];
    const float* be_ua  = (const float*)d_in[26];
    const float* We_au  = (const float*)d_in[27];
    const float* be_au  = (const float*)d_in[28];
    const float* Wp1    = (const float*)d_in[29];
    const float* bp1    = (const float*)d_in[30];
    const float* Wp2    = (const float*)d_in[31];
    const float* bp2    = (const float*)d_in[32];

    float*  outp    = (float*)d_out_v;
    float2* out_ue  = (float2*)outp;                              // [16384][2]
    float*  out_ap  = outp + N_UE * 2;                            // [128][32]
    float2* out_eua = (float2*)(outp + N_UE * 2 + N_AP * 32);     // [E][2]
    float2* out_eau = (float2*)(outp + N_UE * 2 + N_AP * 32 + (size_t)NE * 2);

    float* ws = (float*)d_ws;
    float* x_ueA  = ws;          ws += N_UE * 32;
    float* x_ueB  = ws;          ws += N_UE * 32;
    float* x_apA  = ws;          ws += N_AP * 32;
    float* x_apB  = ws;          ws += N_AP * 32;
    float* agg_ue = ws;          ws += N_UE * 32;
    float* Qua    = ws;          ws += N_UE * 32;
    float* Pau    = ws;          ws += N_AP * 32;
    float2* RueA  = (float2*)ws; ws += N_UE * 2;
    float2* RueB  = (float2*)ws; ws += N_UE * 2;
    float2* RapA  = (float2*)ws; ws += N_AP * 2;
    float2* RapB  = (float2*)ws; ws += N_AP * 2;
    float* partial = ws;         ws += (size_t)NPART * N_AP * 32; // 4 MB
    int* cnt   = (int*)ws;       ws += N_UE;
    int* offs  = (int*)ws;       ws += N_UE + 4;
    int* histD = (int*)ws;       ws += NSB * N_AP;
    int* offsD = (int*)ws;       ws += NSB * N_AP;
    int* invS  = (int*)ws;       ws += NE;                        // 8 MB
    int* invD  = (int*)ws;       ws += NE;                        // 8 MB
    int4* packS = (int4*)ws;     ws += (size_t)NE * 4;            // 32 MB
    int4* packD = (int4*)ws;     ws += (size_t)NE * 4;            // 32 MB
    int* histS = (int*)packS;    // alias: [NSB][N_UE] = 16 MB, dead before packS written
    int* baseS = (int*)packD;    // alias: [NSB][N_UE] = 16 MB, dead before packD written

    dim3 blk(256);
    const size_t aggBytes = (size_t)N_UE * 32 * sizeof(float);

    // ---- sorts ----
    hist_src<<<NSB, blk, 0, stream>>>(src, histS);
    colscan_kernel<<<N_UE / 256, blk, 0, stream>>>(histS, baseS, cnt);
    scan_kernel<<<1, blk, 0, stream>>>(cnt, offs);
    scatter_src<<<NSB, blk, 0, stream>>>(src, dst, e0au, baseS, offs, packS, invS);
    hist_dst<<<NSB, blk, 0, stream>>>(dst, histD);
    scan_dst<<<1, dim3(128), 0, stream>>>(histD, offsD);
    scatter_dst<<<NSB, blk, 0, stream>>>(src, dst, e0ua, offsD, packD, invD);

    init_kernel<<<N_UE * 32 / 256, blk, 0, stream>>>(x_ue, Wm1_ua, bm1_ua, bm1_au, Qua, Pau);

    // ---- layer 1 ----
    hipMemsetAsync(agg_ue, 0, aggBytes, stream);
    edge_pass<false><<<2 * NBLK, blk, 0, stream>>>(
        packS, packD, nullptr, nullptr, nullptr, nullptr, nullptr, nullptr,
        Qua, Pau, Wm1_ua + 32, Wm1_au, agg_ue, partial);
    node_ue_kernel<true, false><<<N_UE / 256, blk, 0, stream>>>(
        x_ue, agg_ue, Wu1_ue, bu1_ue, Wm_ua, bm_ua, We1_ua, We1_au,
        nullptr, nullptr, nullptr, nullptr,
        x_ueA, Qua, RueA, RueB, nullptr);
    node_ap_kernel<true, false><<<N_AP, blk, 0, stream>>>(
        partial, nullptr, Wu1_ap, bu1_ap, Wm_au, bm_au,
        We1_ua + 64, be1_ua, We1_au + 64, be1_au,
        x_apA, Pau, RapA, RapB);

    // ---- layer 2 (EUPD-1 fused) ----
    hipMemsetAsync(agg_ue, 0, aggBytes, stream);
    edge_pass<true><<<2 * NBLK, blk, 0, stream>>>(
        packS, packD, RueA, RueB, RapA, RapB, We1_ua + 128, We1_au + 128,
        Qua, Pau, Wm_ua + 1024, Wm_au + 1024, agg_ue, partial);
    node_ue_kernel<false, false><<<N_UE / 256, blk, 0, stream>>>(
        x_ueA, agg_ue, Wu_ue, bu_ue, Wm_ua + 1088, bm_ua + 32, We_ua, We_au,
        nullptr, nullptr, nullptr, nullptr,
        x_ueB, Qua, RueA, RueB, nullptr);
    node_ap_kernel<false, false><<<N_AP, blk, 0, stream>>>(
        partial, x_apA, Wu_ap, bu_ap, Wm_au + 1088, bm_au + 32,
        We_ua + 64, be_ua, We_au + 64, be_au,
        x_apB, Pau, RapA, RapB);

    // ---- layer 3 (EUPD-2 fused) ----
    hipMemsetAsync(agg_ue, 0, aggBytes, stream);
    edge_pass<true><<<2 * NBLK, blk, 0, stream>>>(
        packS, packD, RueA, RueB, RapA, RapB, We_ua + 128, We_au + 128,
        Qua, Pau, Wm_ua + 2112, Wm_au + 2112, agg_ue, partial);
    node_ue_kernel<false, false><<<N_UE / 256, blk, 0, stream>>>(
        x_ueB, agg_ue, Wu_ue + 2048, bu_ue + 32, Wm_ua + 2176, bm_ua + 64,
        We_ua + 132, We_au + 132,
        nullptr, nullptr, nullptr, nullptr,
        x_ueA, Qua, RueA, RueB, nullptr);
    node_ap_kernel<false, false><<<N_AP, blk, 0, stream>>>(
        partial, x_apB, Wu_ap + 2048, bu_ap + 32, Wm_au + 2176, bm_au + 64,
        We_ua + 196, be_ua + 2, We_au + 196, be_au + 2,
        x_apA, Pau, RapA, RapB);

    // ---- layer 4 (EUPD-3 fused) ----
    hipMemsetAsync(agg_ue, 0, aggBytes, stream);
    edge_pass<true><<<2 * NBLK, blk, 0, stream>>>(
        packS, packD, RueA, RueB, RapA, RapB, We_ua + 260, We_au + 260,
        Qua, Pau, Wm_ua + 3200, Wm_au + 3200, agg_ue, partial);
    node_ue_kernel<false, true><<<N_UE / 256, blk, 0, stream>>>(
        x_ueA, agg_ue, Wu_ue + 4096, bu_ue + 64, nullptr, nullptr,
        We_ua + 264, We_au + 264,
        Wp1, bp1, Wp2, bp2,
        x_ueB, nullptr, RueA, RueB, out_ue);
    node_ap_kernel<false, true><<<N_AP, blk, 0, stream>>>(
        partial, x_apA, Wu_ap + 4096, bu_ap + 64, nullptr, nullptr,
        We_ua + 328, be_ua + 4, We_au + 328, be_au + 4,
        out_ap, nullptr, RapA, RapB);

    // ---- final edge update (layer 4), original order ----
    final_edge<<<NE / 256, blk, 0, stream>>>(
        packS, packD, invS, invD, RueA, RueB, RapA, RapB,
        We_ua + 392, We_au + 392, out_eua, out_eau);
}